// Round 1
// baseline (241.520 us; speedup 1.0000x reference)
//
#include <hip/hip_runtime.h>
#include <math.h>

// Problem constants (fixed by the reference file).
#define S_DIM 2048
#define B_DIM 128
#define P_DIM 1024   // max prefix we size LDS for; actual sep read from device
#define E_DIM 192

// ---------------------------------------------------------------------------
// Kernel 1: per-column prep. One block per column b (128 blocks, 256 thr).
//   - load prefix y[0:sep, b] into LDS (pad to 1024 with +INF)
//   - nanmean reduce -> mean[b]
//   - impute NaN/Inf -> mean in LDS
//   - bitonic sort 1024 elements in LDS
//   - dedupe via block scan -> u[b][0..K), K[b]
// ---------------------------------------------------------------------------
__global__ __launch_bounds__(256) void prep_kernel(
    const float* __restrict__ y, const int* __restrict__ sep_p,
    float* __restrict__ u, int* __restrict__ Kout, float* __restrict__ meanout) {
  __shared__ float sm[P_DIM];
  __shared__ float redf[256];
  __shared__ int   redi[256];
  __shared__ int   scan[256];

  const int b   = blockIdx.x;
  const int tid = threadIdx.x;
  const int sep = *sep_p;  // == 1024 in practice, but read dynamically

  // Load prefix (strided global reads, only 512 KB total across grid) + nan-sum
  float lsum = 0.f;
  int   lcnt = 0;
  for (int i = tid; i < P_DIM; i += 256) {
    float v = (i < sep) ? y[i * B_DIM + b] : INFINITY;
    sm[i] = v;
    if (i < sep && !isnan(v)) { lsum += v; lcnt++; }
  }
  redf[tid] = lsum;
  redi[tid] = lcnt;
  __syncthreads();
  for (int off = 128; off > 0; off >>= 1) {
    if (tid < off) { redf[tid] += redf[tid + off]; redi[tid] += redi[tid + off]; }
    __syncthreads();
  }
  const float mean = redf[0] / (float)redi[0];
  if (tid == 0) meanout[b] = mean;

  // Impute NaN/Inf -> mean (same thread wrote these slots; no barrier needed)
  for (int i = tid; i < sep; i += 256) {
    float v = sm[i];
    if (isnan(v) || isinf(v)) sm[i] = mean;
  }
  __syncthreads();

  // Bitonic sort of 1024 elements, 256 threads (each owns 4 disjoint pairs/stage)
  for (int k = 2; k <= P_DIM; k <<= 1) {
    for (int j = k >> 1; j > 0; j >>= 1) {
      for (int i = tid; i < P_DIM; i += 256) {
        int ixj = i ^ j;
        if (ixj > i) {
          float a = sm[i], c = sm[ixj];
          bool up = ((i & k) == 0);
          if (up ? (a > c) : (a < c)) { sm[i] = c; sm[ixj] = a; }
        }
      }
      __syncthreads();
    }
  }

  // Dedupe: flags + block scan (each thread owns contiguous chunk of 4)
  int flags[4];
  int lu = 0;
  for (int q = 0; q < 4; q++) {
    int i = tid * 4 + q;
    bool nw = (i == 0) || (sm[i] != sm[i - 1]);
    flags[q] = nw ? 1 : 0;
    lu += flags[q];
  }
  scan[tid] = lu;
  __syncthreads();
  // Hillis-Steele inclusive scan over 256 partial sums
  for (int off = 1; off < 256; off <<= 1) {
    int t = (tid >= off) ? scan[tid - off] : 0;
    __syncthreads();
    scan[tid] += t;
    __syncthreads();
  }
  int excl = scan[tid] - lu;
  for (int q = 0; q < 4; q++) {
    int i = tid * 4 + q;
    if (flags[q]) { u[b * P_DIM + excl] = sm[i]; excl++; }
  }
  if (tid == 255) Kout[b] = scan[255];
}

// ---------------------------------------------------------------------------
// Kernel 2: rank + indicator per (s, b). Grid (B, S/256), 256 thr.
// Writes transposed ri[b*S + s] (coalesced).
// ---------------------------------------------------------------------------
__global__ __launch_bounds__(256) void rank_kernel(
    const float* __restrict__ y, const float* __restrict__ u,
    const int* __restrict__ Kv, const float* __restrict__ meanv,
    float2* __restrict__ ri) {
  __shared__ float su[P_DIM];
  const int b = blockIdx.x;
  const int K = Kv[b];
  const float mean = meanv[b];
  for (int i = threadIdx.x; i < K; i += 256) su[i] = u[b * P_DIM + i];
  __syncthreads();

  const int s = blockIdx.y * 256 + threadIdx.x;
  const float v = y[s * B_DIM + b];
  float ind = 0.f;
  float x = v;
  if (isnan(v))      { ind = -2.f; x = mean; }
  else if (isinf(v)) { ind = (v > 0.f) ? 2.f : 4.f; x = mean; }

  // rank = count of unique prefix values strictly < x  (lower_bound)
  int lo = 0, hi = K;
  while (lo < hi) {
    int mid = (lo + hi) >> 1;
    if (su[mid] < x) lo = mid + 1; else hi = mid;
  }
  ri[b * S_DIM + s] = make_float2((float)lo, ind);
}

// ---------------------------------------------------------------------------
// Kernel 3: streaming broadcast write (the 201 MB).
// out[s,b,e] = rank*W[e,0] + ind*W[e,1] + bias[e], float4 stores.
// ---------------------------------------------------------------------------
__global__ __launch_bounds__(256) void out_kernel(
    const float2* __restrict__ ri, const float4* __restrict__ Wf,
    const float4* __restrict__ bias4, float4* __restrict__ out, int total4) {
  const int stride = gridDim.x * blockDim.x;
  for (int idx = blockIdx.x * blockDim.x + threadIdx.x; idx < total4; idx += stride) {
    const int sb = idx / (E_DIM / 4);            // 48 float4 per (s,b)
    const int q  = idx - sb * (E_DIM / 4);
    const int s  = sb >> 7;                      // / B_DIM
    const int b  = sb & (B_DIM - 1);
    const float2 r  = ri[b * S_DIM + s];
    const float4 wa = Wf[2 * q];                 // {W[4q,0],W[4q,1],W[4q+1,0],W[4q+1,1]}
    const float4 wb = Wf[2 * q + 1];
    const float4 bb = bias4[q];
    float4 o;
    o.x = fmaf(r.x, wa.x, fmaf(r.y, wa.y, bb.x));
    o.y = fmaf(r.x, wa.z, fmaf(r.y, wa.w, bb.y));
    o.z = fmaf(r.x, wb.x, fmaf(r.y, wb.y, bb.z));
    o.w = fmaf(r.x, wb.z, fmaf(r.y, wb.w, bb.w));
    out[idx] = o;
  }
}

extern "C" void kernel_launch(void* const* d_in, const int* in_sizes, int n_in,
                              void* d_out, int out_size, void* d_ws, size_t ws_size,
                              hipStream_t stream) {
  const float* y    = (const float*)d_in[0];
  const float* W    = (const float*)d_in[1];
  const float* bias = (const float*)d_in[2];
  const int*   sep  = (const int*)d_in[3];

  // Workspace layout (all 16B-aligned):
  //   [0, 2MB)          ri   : float2[S*B]
  //   [2MB, 2.5MB)      u    : float[B*1024]
  //   [2.5MB, +512B)    K    : int[B]
  //   [... +512B)       mean : float[B]
  char* ws = (char*)d_ws;
  float2* ri    = (float2*)ws;
  float*  u     = (float*)(ws + (size_t)S_DIM * B_DIM * sizeof(float2));
  int*    Kv    = (int*)(ws + (size_t)S_DIM * B_DIM * sizeof(float2)
                            + (size_t)B_DIM * P_DIM * sizeof(float));
  float*  meanv = (float*)((char*)Kv + 512);

  prep_kernel<<<B_DIM, 256, 0, stream>>>(y, sep, u, Kv, meanv);

  dim3 g2(B_DIM, S_DIM / 256);
  rank_kernel<<<g2, 256, 0, stream>>>(y, u, Kv, meanv, ri);

  const int total4 = S_DIM * B_DIM * (E_DIM / 4);  // 12,582,912
  out_kernel<<<2048, 256, 0, stream>>>(ri, (const float4*)W, (const float4*)bias,
                                       (float4*)d_out, total4);
}